// Round 7
// baseline (210.416 us; speedup 1.0000x reference)
//
#include <hip/hip_runtime.h>
#include <hip/hip_bf16.h>

// LGM loss: logits/margin_logits [8192,10000] f32 + scalar likelihood.
// R7: PERSISTENT blocks + store/compute interleave. Evidence: serial-sum of
// phases (writes 102 + LDS 50 + MFMA 20 + reads 19 ~= 190) matches observed
// GEMM time in every config R1-R6; all store-SHAPE experiments null. Theory:
// phase convoy — all co-resident blocks run identical schedules in lockstep,
// so HBM write channel idles during compute phases and saturates in bursts.
// Fix: grid=512 (2/CU, all resident); each block sweeps ~10 tiles; epilogue
// of tile t (held in oacc regs) is emitted in 4 batches interleaved into the
// 4 kc-phases of tile t+1's K-loop -> continuous write stream.

#define ALPHA_ 0.1f
constexpr int BATCH = 8192;
constexpr int NCLS  = 10000;
constexpr int FDIM  = 256;

typedef __attribute__((ext_vector_type(8))) short bf16x8;
typedef __attribute__((ext_vector_type(4))) float f32x4;

__device__ __forceinline__ unsigned short f2bf(float f) {
  unsigned int u = __float_as_uint(f);
  u += 0x7FFF + ((u >> 16) & 1);   // round-to-nearest-even
  return (unsigned short)(u >> 16);
}

// One wave per row: convert f32 row -> bf16 into ws, and compute sum(x*x).
__global__ void prep_kernel(const float* __restrict__ feat,
                            const float* __restrict__ centers,
                            unsigned short* __restrict__ fbf,
                            unsigned short* __restrict__ cbf,
                            float* __restrict__ fsq,
                            float* __restrict__ csq) {
  int gw = (int)((blockIdx.x * blockDim.x + threadIdx.x) >> 6);
  int lane = threadIdx.x & 63;
  if (gw >= BATCH + NCLS) return;
  const float* src; unsigned short* dst; float* sq;
  if (gw < BATCH) {
    src = feat + (size_t)gw * FDIM; dst = fbf + (size_t)gw * FDIM; sq = fsq + gw;
  } else {
    int r = gw - BATCH;
    src = centers + (size_t)r * FDIM; dst = cbf + (size_t)r * FDIM; sq = csq + r;
  }
  float4 v = reinterpret_cast<const float4*>(src)[lane];   // 64 lanes x 16B = 256 f32
  ushort4 b;
  b.x = f2bf(v.x); b.y = f2bf(v.y); b.z = f2bf(v.z); b.w = f2bf(v.w);
  reinterpret_cast<ushort4*>(dst)[lane] = b;
  float s = v.x*v.x + v.y*v.y + v.z*v.z + v.w*v.w;
  #pragma unroll
  for (int off = 32; off >= 1; off >>= 1) s += __shfl_xor(s, off, 64);
  if (lane == 0) *sq = s;
}

// 128x128 tile, BK=64, 8 waves (2Mx4N), each wave 64x32 via 4x2 frags of 16x16x32.
#define BM 128
#define BN 128
#define BK 64
#define GRID 512
constexpr int NTN = 79;                 // N tiles
constexpr int NWG = (BATCH / BM) * NTN; // 5056 == 8 * 632

__global__ __launch_bounds__(512, 4)
void gemm_kernel(const unsigned short* __restrict__ fbf,
                 const unsigned short* __restrict__ cbf,
                 const float* __restrict__ fsq,
                 const float* __restrict__ csq,
                 const int* __restrict__ label,
                 float* __restrict__ out_logits,
                 float* __restrict__ out_margin,
                 float* __restrict__ lik_row) {
  // Double-buffered, XOR-swizzled (slot = chunk ^ (row&7), 16B chunks).
  __shared__ unsigned short As[2][BM * BK];   // 16 KB each
  __shared__ unsigned short Bs[2][BN * BK];   // 16 KB each

  const int bid  = blockIdx.x;          // 0..511; (t&7)==(bid&7) for all steps
  const int tid  = threadIdx.x;
  const int lane = tid & 63;
  const int wid  = tid >> 6;            // 0..7
  const int wr   = (wid >> 2) * 64;     // 2 waves in M
  const int wc   = (wid & 3) * 32;      // 4 waves in N
  const int sr   = tid >> 3;            // staging row 0..63
  const int sc   = tid & 7;             // staging 16B chunk 0..7
  const int mloc  = wr + (lane & 15);
  const int nbase = wc + ((lane >> 4) << 2);

  f32x4 acc[4][2];   // current tile accumulator
  f32x4 oacc[4][2];  // previous tile's finished logits (pending stores)
  int   plb[4];      // previous tile's labels per i-row
  int   pmb = 0, pc0 = 0;

  bf16x8 va[2], vb[2];

  #define LOADT(abase_, c0_, k0_) do {                                         \
    _Pragma("unroll")                                                          \
    for (int j = 0; j < 2; ++j) {                                              \
      int r = j * 64 + sr;                                                     \
      va[j] = *reinterpret_cast<const bf16x8*>(fbf + (abase_) + (size_t)r * FDIM + (k0_) + sc * 8); \
      int cc = (c0_) + r; cc = (cc < NCLS) ? cc : (NCLS - 1);                  \
      vb[j] = *reinterpret_cast<const bf16x8*>(cbf + (size_t)cc * FDIM + (k0_) + sc * 8); \
    }                                                                          \
  } while (0)

  #define STORET(b_) do {                                                      \
    _Pragma("unroll")                                                          \
    for (int j = 0; j < 2; ++j) {                                              \
      int r = j * 64 + sr;                                                     \
      int off = r * BK + ((sc ^ (r & 7)) * 8);                                 \
      *reinterpret_cast<bf16x8*>(&As[b_][off]) = va[j];                        \
      *reinterpret_cast<bf16x8*>(&Bs[b_][off]) = vb[j];                        \
    }                                                                          \
  } while (0)

  // Emit pending-store batch for row-group i_ (compile-time constant).
  #define EMIT(i_) do {                                                        \
    int m_ = pmb + (i_) * 16;                                                  \
    size_t rowoff_ = (size_t)m_ * NCLS;                                        \
    int lb_ = plb[i_];                                                         \
    _Pragma("unroll")                                                          \
    for (int j = 0; j < 2; ++j) {                                              \
      int n0_ = pc0 + nbase + j * 16;                                          \
      if (n0_ < NCLS) {                                                        \
        f32x4 lg_ = oacc[i_][j];                                               \
        *reinterpret_cast<f32x4*>(&out_logits[rowoff_ + n0_]) = lg_;           \
        f32x4 mg_;                                                             \
        mg_[0] = (lb_ == n0_    ) ? lg_[0] * (1.0f + ALPHA_) : lg_[0];         \
        mg_[1] = (lb_ == n0_ + 1) ? lg_[1] * (1.0f + ALPHA_) : lg_[1];         \
        mg_[2] = (lb_ == n0_ + 2) ? lg_[2] * (1.0f + ALPHA_) : lg_[2];         \
        mg_[3] = (lb_ == n0_ + 3) ? lg_[3] * (1.0f + ALPHA_) : lg_[3];         \
        *reinterpret_cast<f32x4*>(&out_margin[rowoff_ + n0_]) = mg_;           \
        if (lb_ >= n0_ && lb_ < n0_ + 4) {                                     \
          float v_ = (lb_ == n0_) ? lg_[0] : (lb_ == n0_ + 1) ? lg_[1]         \
                   : (lb_ == n0_ + 2) ? lg_[2] : lg_[3];                       \
          lik_row[m_] = -v_;                                                   \
        }                                                                      \
      }                                                                        \
    }                                                                          \
  } while (0)

  for (int t = bid; t < NWG; t += GRID) {
    // tile index -> (mt, nt): XCD-chunked, nt-fastest (concurrent blocks of an
    // XCD cover ~64 consecutive nt of one mt band -> A-panel L2 reuse).
    int wg = (t & 7) * (NWG / 8) + (t >> 3);
    int mt = wg / NTN;
    int nt = wg - mt * NTN;
    size_t a_base = (size_t)(mt * BM) * FDIM;
    int c0 = nt * BN;
    const int pend = (t != bid);   // block-uniform

    #pragma unroll
    for (int i = 0; i < 4; i++)
      #pragma unroll
      for (int j = 0; j < 2; j++) acc[i][j] = (f32x4){0.f, 0.f, 0.f, 0.f};

    LOADT(a_base, c0, 0);
    STORET(0);

    #pragma unroll
    for (int kc = 0; kc < FDIM / BK; ++kc) {
      const int cur = kc & 1;
      if (kc < FDIM / BK - 1) LOADT(a_base, c0, (kc + 1) * BK);
      __syncthreads();                          // buf[cur] writes visible
      #pragma unroll
      for (int kk = 0; kk < BK / 32; ++kk) {
        const int ch = kk * 4 + (lane >> 4);    // 16B chunk within row
        bf16x8 a[4], b[2];
        #pragma unroll
        for (int i = 0; i < 4; i++) {
          int row = wr + i * 16 + (lane & 15);
          a[i] = *reinterpret_cast<const bf16x8*>(&As[cur][row * BK + ((ch ^ (row & 7)) * 8)]);
        }
        #pragma unroll
        for (int j = 0; j < 2; j++) {
          int row = wc + j * 16 + (lane & 15);
          b[j] = *reinterpret_cast<const bf16x8*>(&Bs[cur][row * BK + ((ch ^ (row & 7)) * 8)]);
        }
        #pragma unroll
        for (int i = 0; i < 4; i++)
          #pragma unroll
          for (int j = 0; j < 2; j++)
            acc[i][j] = __builtin_amdgcn_mfma_f32_16x16x32_bf16(b[j], a[i], acc[i][j], 0, 0, 0);
      }
      // Interleave one quarter of the previous tile's stores into this phase.
      if (pend) { EMIT(kc); }
      if (kc < FDIM / BK - 1) STORET(cur ^ 1);  // fill other buffer
    }

    // Fold row/col terms: oacc = acc - 0.5*(fsq+csq); save label/coords.
    #pragma unroll
    for (int i = 0; i < 4; i++) {
      int m = mt * BM + mloc + i * 16;
      float fs = fsq[m];
      plb[i] = label[m];
      #pragma unroll
      for (int j = 0; j < 2; j++) {
        int n0 = c0 + nbase + j * 16;
        int nc = (n0 <= NCLS - 4) ? n0 : (NCLS - 4);   // clamp csq read
        float4 cs = *reinterpret_cast<const float4*>(&csq[nc]);
        oacc[i][j][0] = acc[i][j][0] - 0.5f * (fs + cs.x);
        oacc[i][j][1] = acc[i][j][1] - 0.5f * (fs + cs.y);
        oacc[i][j][2] = acc[i][j][2] - 0.5f * (fs + cs.z);
        oacc[i][j][3] = acc[i][j][3] - 0.5f * (fs + cs.w);
      }
    }
    pmb = mt * BM + mloc;
    pc0 = c0;
  }

  // Final flush of the last tile's stores.
  EMIT(0); EMIT(1); EMIT(2); EMIT(3);

  #undef LOADT
  #undef STORET
  #undef EMIT
}

// likelihood = (1/B) * sum_m lik_row[m]; 1024 threads, deterministic tree.
__global__ void lik_reduce_kernel(const float* __restrict__ lik_row,
                                  float* __restrict__ out) {
  int t = threadIdx.x;  // 1024
  float v = 0.f;
  #pragma unroll
  for (int i = 0; i < BATCH / 1024; i++) v += lik_row[t + i * 1024];
  #pragma unroll
  for (int off = 32; off >= 1; off >>= 1) v += __shfl_xor(v, off, 64);
  __shared__ float red[16];
  if ((t & 63) == 0) red[t >> 6] = v;
  __syncthreads();
  if (t == 0) {
    float s = 0.f;
    #pragma unroll
    for (int i = 0; i < 16; i++) s += red[i];
    out[0] = s * (1.0f / BATCH);
  }
}

extern "C" void kernel_launch(void* const* d_in, const int* in_sizes, int n_in,
                              void* d_out, int out_size, void* d_ws, size_t ws_size,
                              hipStream_t stream) {
  const float* feat    = (const float*)d_in[0];
  const int*   label   = (const int*)d_in[1];
  const float* centers = (const float*)d_in[2];

  float* out        = (float*)d_out;
  float* out_logits = out;
  float* out_margin = out + (size_t)BATCH * NCLS;
  float* out_lik    = out + 2 * (size_t)BATCH * NCLS;

  char* ws = (char*)d_ws;
  unsigned short* fbf = (unsigned short*)ws;                                   // 4 MB
  unsigned short* cbf = (unsigned short*)(ws + (size_t)BATCH * FDIM * 2);      // 5 MB
  float* fsq     = (float*)(ws + (size_t)BATCH * FDIM * 2 + (size_t)NCLS * FDIM * 2);
  float* csq     = fsq + BATCH;
  float* lik_row = csq + NCLS;

  prep_kernel<<<(BATCH + NCLS) / 4, 256, 0, stream>>>(feat, centers, fbf, cbf, fsq, csq);
  gemm_kernel<<<GRID, 512, 0, stream>>>(
      fbf, cbf, fsq, csq, label, out_logits, out_margin, lik_row);
  lik_reduce_kernel<<<1, 1024, 0, stream>>>(lik_row, out_lik);
}